// Round 9
// baseline (124.561 us; speedup 1.0000x reference)
//
#include <hip/hip_runtime.h>
#include <math.h>

#define BB   8
#define CC   256
#define HH   56
#define WW   56
#define KK   3
#define MIDN 51
#define NTAP (KK*KK)          // 9
#define CKK  (CC*NTAP)        // 2304
#define HW   (HH*WW)          // 3136
#define SPIX 64               // pixels per K1 strip
#define NSTR (HW/SPIX)        // 49 strips, exact
#define CPR  128              // channels per K1 round (2 rounds)
#define XSTR 65               // K1 LDS tile stride: bank (c+p)%32, <=2 lanes/bank
#define NCPB 2                // channels per ddf block (halved for occupancy)
#define TILE 3364             // 58*58 halo tile

// ============ K1: sf (full channel reduction + norm) + pooled-mean partials ============
// grid: BB*NSTR = 392 blocks, 256 threads. Each block owns 64 pixels and ALL 256
// channels (2 rounds of 128 through LDS). Writes sf directly (normalized).
__global__ __launch_bounds__(256) void k_sf(const float* __restrict__ x,
                                            const float* __restrict__ ws,
                                            const float* __restrict__ bs,
                                            float* __restrict__ sf,
                                            float* __restrict__ poolpart) {
    int blk = blockIdx.x;
    int s = blk % NSTR;
    int b = blk / NSTR;
    int t = threadIdx.x;
    int p = t & 63;           // pixel within strip
    int q = t >> 6;           // channel quarter (32 channels per round)
    __shared__ float xs[CPR * XSTR];          // [128 ch][65] = 33.3 KB
    __shared__ float wss[NTAP][CC];           // 9 KB
    __shared__ float accq[NTAP * 4 * SPIX];   // 9 KB
    for (int idx = t; idx < NTAP * CC; idx += 256)
        ((float*)wss)[idx] = ws[idx];         // ws is (9,256) row-major
    float acc[NTAP];
    #pragma unroll
    for (int n = 0; n < NTAP; ++n) acc[n] = 0.f;
    const float* xb = x + ((size_t)b * CC) * HW + s * SPIX;
    #pragma unroll
    for (int r = 0; r < 2; ++r) {
        if (r) __syncthreads();               // round-0 readers done before restage
        // stage 32 channels per thread: load to regs, then LDS (transposed)
        float vv[32];
        #pragma unroll
        for (int c = 0; c < 32; ++c)
            vv[c] = xb[(size_t)(r * CPR + q * 32 + c) * HW + p];
        #pragma unroll
        for (int c = 0; c < 32; ++c)
            xs[(q * 32 + c) * XSTR + p] = vv[c];
        __syncthreads();
        // pool: per-channel sum over the 64 strip pixels (threads 0..127)
        if (t < CPR) {
            float sum = 0.f;
            #pragma unroll 8
            for (int pp = 0; pp < SPIX; ++pp) sum += xs[t * XSTR + pp];
            poolpart[((size_t)(b * NSTR + s)) * CC + r * CPR + t] = sum;
        }
        // dot: 32 channels x 9 taps per thread
        #pragma unroll 4
        for (int c = 0; c < 32; ++c) {
            float xv = xs[(q * 32 + c) * XSTR + p];
            #pragma unroll
            for (int n = 0; n < NTAP; ++n)
                acc[n] += xv * wss[n][r * CPR + q * 32 + c];
        }
    }
    #pragma unroll
    for (int n = 0; n < NTAP; ++n) accq[(n * 4 + q) * SPIX + p] = acc[n];
    __syncthreads();
    if (t < SPIX) {
        float y[NTAP];
        #pragma unroll
        for (int n = 0; n < NTAP; ++n) {
            float v = bs[n];
            #pragma unroll
            for (int qq = 0; qq < 4; ++qq) v += accq[(n * 4 + qq) * SPIX + t];
            y[n] = v;
        }
        float mean = 0.f;
        #pragma unroll
        for (int n = 0; n < NTAP; ++n) mean += y[n];
        mean *= (1.f / NTAP);
        float var = 0.f;
        #pragma unroll
        for (int n = 0; n < NTAP; ++n) { float d = y[n] - mean; var += d * d; }
        float inv = 0.47140452079103173f /    // GAIN/K = sqrt(2)/3
                    (sqrtf(var * (1.f / (NTAP - 1))) + 1e-10f);
        #pragma unroll
        for (int n = 0; n < NTAP; ++n)
            sf[((size_t)(b * NTAP + n)) * HW + s * SPIX + t] = (y[n] - mean) * inv;
    }
}

// ============ K2: DDF apply, inline MLP, column-sliding window, NCPB=2 ============
// grid: BB*CC/NCPB = 1024 blocks, 448 threads (7 waves). LDS 26.9+1.6 KB ->
// 4 blocks/CU, ~28 waves/CU (2x round-8's 14): the round-8 post-mortem showed
// the LDS-read cut barely paid -> kernel is LATENCY-bound, so this trades
// 2x sf L2 re-reads (58->116 MB, cheap at L2 BW) for 2x wave concurrency.
// Same proven column-sliding structure: thread owns col j=t%56, 7 rows;
// 12 new LDS reads/px, stride-1 bank pattern, coalesced sf/out.
__global__ __launch_bounds__(448, 4) void k_ddf(const float* __restrict__ x,
                                                const float* __restrict__ poolpart,
                                                const float* __restrict__ w1,
                                                const float* __restrict__ b1,
                                                const float* __restrict__ w2,
                                                const float* __restrict__ b2,
                                                const float* __restrict__ fn_std,
                                                const float* __restrict__ sf,
                                                float* __restrict__ out) {
    int blk = blockIdx.x;
    int b = blk / (CC / NCPB), cg = blk % (CC / NCPB);
    int c0 = cg * NCPB;
    int t = threadIdx.x;
    __shared__ float xt[NCPB][TILE];          // 26.9 KB
    __shared__ float ps[CC];                  // pooled means
    __shared__ float y1s[64];                 // 51 used
    __shared__ float y2s[NCPB * NTAP];        // 18
    __shared__ float cfs[NCPB * NTAP];        // 18
    for (int idx = t; idx < NCPB * TILE; idx += 448) ((float*)xt)[idx] = 0.f;
    __syncthreads();
    // stage 2 contiguous planes with float4 loads (1568 float4s)
    const float4* xp4 = (const float4*)(x + ((size_t)(b * CC + c0)) * HW);
    for (int i4 = t; i4 < NCPB * HW / 4; i4 += 448) {
        float4 v = xp4[i4];
        int k = i4 / (HW / 4);                 // plane
        int rem4 = i4 - k * (HW / 4);          // float4 index within plane
        int r = rem4 / (WW / 4);               // row
        int col = 4 * (rem4 - r * (WW / 4));   // col (multiple of 4)
        float* d = &xt[k][(r + 1) * 58 + col + 1];
        d[0] = v.x; d[1] = v.y; d[2] = v.z; d[3] = v.w;
    }
    // ---- inline MLP (overlaps with staging latency + other resident blocks) ----
    if (t < CC) {
        float s = 0.f;
        const float* pp = poolpart + ((size_t)b * NSTR) * CC + t;
        for (int st = 0; st < NSTR; ++st) s += pp[(size_t)st * CC];
        ps[t] = s * (1.0f / HW);
    }
    __syncthreads();
    if (t < MIDN) {
        float a = b1[t];
        const float* wr = w1 + t * CC;
        for (int c2 = 0; c2 < CC; ++c2) a += ps[c2] * wr[c2];
        y1s[t] = fmaxf(a, 0.f);
    }
    __syncthreads();
    if (t < NCPB * NTAP) {
        int row = c0 * NTAP + t;               // (c0+k)*9+q
        float a = b2[row];
        const float* r = w2 + (size_t)row * MIDN;
        #pragma unroll 3
        for (int m = 0; m < MIDN; ++m) a += y1s[m] * r[m];
        y2s[t] = a;
    }
    __syncthreads();
    if (t < NCPB) {
        float y2[NTAP];
        #pragma unroll
        for (int q = 0; q < NTAP; ++q) y2[q] = y2s[t * NTAP + q];
        float mean = 0.f;
        #pragma unroll
        for (int q = 0; q < NTAP; ++q) mean += y2[q];
        mean *= (1.f / NTAP);
        float var = 0.f;
        #pragma unroll
        for (int q = 0; q < NTAP; ++q) { float d = y2[q] - mean; var += d * d; }
        float inv = 1.f / (sqrtf(var * (1.f / (NTAP - 1))) + 1e-10f);
        #pragma unroll
        for (int q = 0; q < NTAP; ++q)
            cfs[t * NTAP + q] = (y2[q] - mean) * inv * fn_std[(c0 + t) * NTAP + q];
    }
    __syncthreads();
    float cf9[NCPB][NTAP];
    #pragma unroll
    for (int k = 0; k < NCPB; ++k)
        #pragma unroll
        for (int n = 0; n < NTAP; ++n) cf9[k][n] = cfs[k * NTAP + n];
    // ---- ddf apply: column-sliding window ----
    int j = t % WW;            // column 0..55
    int oct = t / WW;          // 0..7
    int i0 = oct * 7;          // first output row
    const float* sfb = sf + (size_t)b * NTAP * HW + j;
    float* op = out + ((size_t)(b * CC + c0)) * HW + j;
    // window regs: wr0/wr1/wr2 = tile rows i, i+1, i+2; cols j..j+2 per channel
    float wr0[NCPB][3], wr1[NCPB][3], wr2[NCPB][3];
    #pragma unroll
    for (int k = 0; k < NCPB; ++k)
        #pragma unroll
        for (int c = 0; c < 3; ++c) {
            wr0[k][c] = xt[k][(i0    ) * 58 + j + c];
            wr1[k][c] = xt[k][(i0 + 1) * 58 + j + c];
        }
    #pragma unroll
    for (int s = 0; s < 7; ++s) {
        int i = i0 + s;
        // load new bottom row (tile row i+2)
        #pragma unroll
        for (int k = 0; k < NCPB; ++k)
            #pragma unroll
            for (int c = 0; c < 3; ++c)
                wr2[k][c] = xt[k][(i + 2) * 58 + j + c];
        // sf taps for this pixel (coalesced: consecutive lanes -> consecutive j)
        float s9[NTAP];
        #pragma unroll
        for (int n = 0; n < NTAP; ++n) s9[n] = sfb[(size_t)n * HW + i * WW];
        #pragma unroll
        for (int k = 0; k < NCPB; ++k) {
            float a = 0.f;
            #pragma unroll
            for (int c = 0; c < 3; ++c) {
                a += wr0[k][c] * (cf9[k][0 * 3 + c] * s9[0 * 3 + c]);
                a += wr1[k][c] * (cf9[k][1 * 3 + c] * s9[1 * 3 + c]);
                a += wr2[k][c] * (cf9[k][2 * 3 + c] * s9[2 * 3 + c]);
            }
            op[(size_t)k * HW + i * WW] = a;
        }
        // rotate window down
        #pragma unroll
        for (int k = 0; k < NCPB; ++k)
            #pragma unroll
            for (int c = 0; c < 3; ++c) {
                wr0[k][c] = wr1[k][c];
                wr1[k][c] = wr2[k][c];
            }
    }
}

extern "C" void kernel_launch(void* const* d_in, const int* in_sizes, int n_in,
                              void* d_out, int out_size, void* d_ws, size_t ws_size,
                              hipStream_t stream) {
    const float* x      = (const float*)d_in[0];
    const float* w1     = (const float*)d_in[1];
    const float* b1     = (const float*)d_in[2];
    const float* w2     = (const float*)d_in[3];
    const float* b2     = (const float*)d_in[4];
    const float* ws     = (const float*)d_in[5];
    const float* bs     = (const float*)d_in[6];
    const float* fn_std = (const float*)d_in[7];
    float* out = (float*)d_out;

    float* wsf      = (float*)d_ws;
    float* sf       = wsf;                         // BB*NTAP*HW = 225792
    float* poolpart = sf + 225792;                 // BB*NSTR*CC = 100352

    k_sf<<<BB * NSTR, 256, 0, stream>>>(x, ws, bs, sf, poolpart);
    k_ddf<<<BB * (CC / NCPB), 448, 0, stream>>>(x, poolpart, w1, b1, w2, b2,
                                                fn_std, sf, out);
}

// Round 10
// 113.732 us; speedup vs baseline: 1.0952x; 1.0952x over previous
//
#include <hip/hip_runtime.h>
#include <math.h>

#define BB   8
#define CC   256
#define HH   56
#define WW   56
#define KK   3
#define MIDN 51
#define NTAP (KK*KK)          // 9
#define CKK  (CC*NTAP)        // 2304
#define HW   (HH*WW)          // 3136
#define SPIX 64               // pixels per K1 strip
#define NSTR (HW/SPIX)        // 49 strips, exact
#define CPR  128              // channels per K1 round (2 rounds)
#define XSTR 65               // K1 LDS tile stride: bank (c+p)%32, <=2 lanes/bank
#define NCPB 4                // channels per ddf block (r9 measured NCPB=2 worse)
#define TILE 3364             // 58*58 halo tile

// ============ K1: sf (full channel reduction + norm) + pooled-mean partials ============
// grid: BB*NSTR = 392 blocks, 256 threads. Each block owns 64 pixels and ALL 256
// channels (2 rounds of 128 through LDS). Writes sf directly (normalized).
__global__ __launch_bounds__(256) void k_sf(const float* __restrict__ x,
                                            const float* __restrict__ ws,
                                            const float* __restrict__ bs,
                                            float* __restrict__ sf,
                                            float* __restrict__ poolpart) {
    int blk = blockIdx.x;
    int s = blk % NSTR;
    int b = blk / NSTR;
    int t = threadIdx.x;
    int p = t & 63;           // pixel within strip
    int q = t >> 6;           // channel quarter (32 channels per round)
    __shared__ float xs[CPR * XSTR];          // [128 ch][65] = 33.3 KB
    __shared__ float wss[NTAP][CC];           // 9 KB
    __shared__ float accq[NTAP * 4 * SPIX];   // 9 KB
    for (int idx = t; idx < NTAP * CC; idx += 256)
        ((float*)wss)[idx] = ws[idx];         // ws is (9,256) row-major
    float acc[NTAP];
    #pragma unroll
    for (int n = 0; n < NTAP; ++n) acc[n] = 0.f;
    const float* xb = x + ((size_t)b * CC) * HW + s * SPIX;
    #pragma unroll
    for (int r = 0; r < 2; ++r) {
        if (r) __syncthreads();               // round-0 readers done before restage
        // stage 32 channels per thread: load to regs, then LDS (transposed)
        float vv[32];
        #pragma unroll
        for (int c = 0; c < 32; ++c)
            vv[c] = xb[(size_t)(r * CPR + q * 32 + c) * HW + p];
        #pragma unroll
        for (int c = 0; c < 32; ++c)
            xs[(q * 32 + c) * XSTR + p] = vv[c];
        __syncthreads();
        // pool: per-channel sum over the 64 strip pixels (threads 0..127)
        if (t < CPR) {
            float sum = 0.f;
            #pragma unroll 8
            for (int pp = 0; pp < SPIX; ++pp) sum += xs[t * XSTR + pp];
            poolpart[((size_t)(b * NSTR + s)) * CC + r * CPR + t] = sum;
        }
        // dot: 32 channels x 9 taps per thread
        #pragma unroll 4
        for (int c = 0; c < 32; ++c) {
            float xv = xs[(q * 32 + c) * XSTR + p];
            #pragma unroll
            for (int n = 0; n < NTAP; ++n)
                acc[n] += xv * wss[n][r * CPR + q * 32 + c];
        }
    }
    #pragma unroll
    for (int n = 0; n < NTAP; ++n) accq[(n * 4 + q) * SPIX + p] = acc[n];
    __syncthreads();
    if (t < SPIX) {
        float y[NTAP];
        #pragma unroll
        for (int n = 0; n < NTAP; ++n) {
            float v = bs[n];
            #pragma unroll
            for (int qq = 0; qq < 4; ++qq) v += accq[(n * 4 + qq) * SPIX + t];
            y[n] = v;
        }
        float mean = 0.f;
        #pragma unroll
        for (int n = 0; n < NTAP; ++n) mean += y[n];
        mean *= (1.f / NTAP);
        float var = 0.f;
        #pragma unroll
        for (int n = 0; n < NTAP; ++n) { float d = y[n] - mean; var += d * d; }
        float inv = 0.47140452079103173f /    // GAIN/K = sqrt(2)/3
                    (sqrtf(var * (1.f / (NTAP - 1))) + 1e-10f);
        #pragma unroll
        for (int n = 0; n < NTAP; ++n)
            sf[((size_t)(b * NTAP + n)) * HW + s * SPIX + t] = (y[n] - mean) * inv;
    }
}

// ============ K2: DDF apply, inline MLP, column-sliding register window ============
// grid: BB*CC/NCPB = 512 blocks, 448 threads (7 waves). Thread t owns column
// j=t%56, rows oct*7..oct*7+6 (oct=t/56). 3x3x4ch input window in registers:
// slide down = 12 new LDS reads/pixel (vs 36 scalar) with stride-1 bank
// pattern (2 lanes/bank, free), coalesced sf loads + out stores.
// NCPB=4 is the measured optimum: r9's NCPB=2 (1024 blocks) regressed +10.7us
// (per-block MLP-prologue redundancy + doubled sf traffic beat the occupancy
// gain); r1/r6 b128 variants spilled/conflicted. LDS 55.4 KB -> 2 blocks/CU.
__global__ __launch_bounds__(448, 3) void k_ddf(const float* __restrict__ x,
                                                const float* __restrict__ poolpart,
                                                const float* __restrict__ w1,
                                                const float* __restrict__ b1,
                                                const float* __restrict__ w2,
                                                const float* __restrict__ b2,
                                                const float* __restrict__ fn_std,
                                                const float* __restrict__ sf,
                                                float* __restrict__ out) {
    int blk = blockIdx.x;
    int b = blk / (CC / NCPB), cg = blk % (CC / NCPB);
    int c0 = cg * NCPB;
    int t = threadIdx.x;
    __shared__ float xt[NCPB][TILE];          // 53.8 KB
    __shared__ float ps[CC];                  // pooled means
    __shared__ float y1s[64];                 // 51 used
    __shared__ float y2s[NCPB * NTAP];        // 36
    __shared__ float cfs[NCPB * NTAP];        // 36
    for (int idx = t; idx < NCPB * TILE; idx += 448) ((float*)xt)[idx] = 0.f;
    __syncthreads();
    // stage 4 contiguous planes with float4 loads (3136 float4s = 7/thread)
    const float4* xp4 = (const float4*)(x + ((size_t)(b * CC + c0)) * HW);
    for (int i4 = t; i4 < NCPB * HW / 4; i4 += 448) {
        float4 v = xp4[i4];
        int k = i4 / (HW / 4);                 // plane
        int rem4 = i4 - k * (HW / 4);          // float4 index within plane
        int r = rem4 / (WW / 4);               // row
        int col = 4 * (rem4 - r * (WW / 4));   // col (multiple of 4)
        float* d = &xt[k][(r + 1) * 58 + col + 1];
        d[0] = v.x; d[1] = v.y; d[2] = v.z; d[3] = v.w;
    }
    // ---- inline MLP (overlaps with staging latency) ----
    if (t < CC) {
        float s = 0.f;
        const float* pp = poolpart + ((size_t)b * NSTR) * CC + t;
        for (int st = 0; st < NSTR; ++st) s += pp[(size_t)st * CC];
        ps[t] = s * (1.0f / HW);
    }
    __syncthreads();
    if (t < MIDN) {
        float a = b1[t];
        const float* wr = w1 + t * CC;
        for (int c2 = 0; c2 < CC; ++c2) a += ps[c2] * wr[c2];
        y1s[t] = fmaxf(a, 0.f);
    }
    __syncthreads();
    if (t < NCPB * NTAP) {
        int row = c0 * NTAP + t;               // (c0+k)*9+q
        float a = b2[row];
        const float* r = w2 + (size_t)row * MIDN;
        #pragma unroll 3
        for (int m = 0; m < MIDN; ++m) a += y1s[m] * r[m];
        y2s[t] = a;
    }
    __syncthreads();
    if (t < NCPB) {
        float y2[NTAP];
        #pragma unroll
        for (int q = 0; q < NTAP; ++q) y2[q] = y2s[t * NTAP + q];
        float mean = 0.f;
        #pragma unroll
        for (int q = 0; q < NTAP; ++q) mean += y2[q];
        mean *= (1.f / NTAP);
        float var = 0.f;
        #pragma unroll
        for (int q = 0; q < NTAP; ++q) { float d = y2[q] - mean; var += d * d; }
        float inv = 1.f / (sqrtf(var * (1.f / (NTAP - 1))) + 1e-10f);
        #pragma unroll
        for (int q = 0; q < NTAP; ++q)
            cfs[t * NTAP + q] = (y2[q] - mean) * inv * fn_std[(c0 + t) * NTAP + q];
    }
    __syncthreads();
    float cf9[NCPB][NTAP];
    #pragma unroll
    for (int k = 0; k < NCPB; ++k)
        #pragma unroll
        for (int n = 0; n < NTAP; ++n) cf9[k][n] = cfs[k * NTAP + n];
    // ---- ddf apply: column-sliding window ----
    int j = t % WW;            // column 0..55
    int oct = t / WW;          // 0..7
    int i0 = oct * 7;          // first output row
    const float* sfb = sf + (size_t)b * NTAP * HW + j;
    float* op = out + ((size_t)(b * CC + c0)) * HW + j;
    // window regs: wr0/wr1/wr2 = tile rows i, i+1, i+2; cols j..j+2 per channel
    float wr0[NCPB][3], wr1[NCPB][3], wr2[NCPB][3];
    #pragma unroll
    for (int k = 0; k < NCPB; ++k)
        #pragma unroll
        for (int c = 0; c < 3; ++c) {
            wr0[k][c] = xt[k][(i0    ) * 58 + j + c];
            wr1[k][c] = xt[k][(i0 + 1) * 58 + j + c];
        }
    #pragma unroll
    for (int s = 0; s < 7; ++s) {
        int i = i0 + s;
        // load new bottom row (tile row i+2)
        #pragma unroll
        for (int k = 0; k < NCPB; ++k)
            #pragma unroll
            for (int c = 0; c < 3; ++c)
                wr2[k][c] = xt[k][(i + 2) * 58 + j + c];
        // sf taps for this pixel (coalesced: consecutive lanes -> consecutive j)
        float s9[NTAP];
        #pragma unroll
        for (int n = 0; n < NTAP; ++n) s9[n] = sfb[(size_t)n * HW + i * WW];
        #pragma unroll
        for (int k = 0; k < NCPB; ++k) {
            float a = 0.f;
            #pragma unroll
            for (int c = 0; c < 3; ++c) {
                a += wr0[k][c] * (cf9[k][0 * 3 + c] * s9[0 * 3 + c]);
                a += wr1[k][c] * (cf9[k][1 * 3 + c] * s9[1 * 3 + c]);
                a += wr2[k][c] * (cf9[k][2 * 3 + c] * s9[2 * 3 + c]);
            }
            op[(size_t)k * HW + i * WW] = a;
        }
        // rotate window down
        #pragma unroll
        for (int k = 0; k < NCPB; ++k)
            #pragma unroll
            for (int c = 0; c < 3; ++c) {
                wr0[k][c] = wr1[k][c];
                wr1[k][c] = wr2[k][c];
            }
    }
}

extern "C" void kernel_launch(void* const* d_in, const int* in_sizes, int n_in,
                              void* d_out, int out_size, void* d_ws, size_t ws_size,
                              hipStream_t stream) {
    const float* x      = (const float*)d_in[0];
    const float* w1     = (const float*)d_in[1];
    const float* b1     = (const float*)d_in[2];
    const float* w2     = (const float*)d_in[3];
    const float* b2     = (const float*)d_in[4];
    const float* ws     = (const float*)d_in[5];
    const float* bs     = (const float*)d_in[6];
    const float* fn_std = (const float*)d_in[7];
    float* out = (float*)d_out;

    float* wsf      = (float*)d_ws;
    float* sf       = wsf;                         // BB*NTAP*HW = 225792
    float* poolpart = sf + 225792;                 // BB*NSTR*CC = 100352

    k_sf<<<BB * NSTR, 256, 0, stream>>>(x, ws, bs, sf, poolpart);
    k_ddf<<<BB * (CC / NCPB), 448, 0, stream>>>(x, poolpart, w1, b1, w2, b2,
                                                fn_std, sf, out);
}